// Round 1
// baseline (538.180 us; speedup 1.0000x reference)
//
#include <hip/hip_runtime.h>

#define Bsz 8
#define Nn  512
#define Dd  768
#define Ll  16

// ws layout: At [B*L*N floats] | Bt [B*L*N floats] | acc[8] (u32 x4 counts, float span_num, float se_sum)
// acc idx: 0=tp 1=tn 2=fp 3=valc 4=span_num(f32) 5=se_sum(f32)

// ---------------------------------------------------------------------------
// Kernel 1: per 8-row group of x, compute all 64 dot products (32 se cols,
// 16 a-cols, 16 bb-cols), do the start/end focal loss inline, store At/Bt
// transposed to [ (b*L+l)*N + n ] for coalesced reads in kernel 2.
// ---------------------------------------------------------------------------
__global__ __launch_bounds__(256) void k_prep(
    const float* __restrict__ x, const float* __restrict__ start,
    const float* __restrict__ end, const int* __restrict__ seqlen,
    const float* __restrict__ W_se, const float* __restrict__ b_se,
    const float* __restrict__ W_span, const float* __restrict__ b_span,
    float* __restrict__ At, float* __restrict__ Bt, float* __restrict__ acc)
{
    __shared__ float xs[8 * Dd];        // 24 KB
    __shared__ float part[256 * 8];     // 8 KB
    __shared__ float s_se;

    const int tid = threadIdx.x;
    const int blk = blockIdx.x;         // 512 blocks: b*64 + group
    const int b   = blk >> 6;
    const int n0  = (blk & 63) * 8;

    if (tid == 0) s_se = 0.0f;

    // load 8 rows of x (8*768 floats) via float4
    const float4* xsrc = (const float4*)(x + (size_t)(b * Nn + n0) * Dd);
    float4* xd = (float4*)xs;
    for (int i = tid; i < 8 * Dd / 4; i += 256) xd[i] = xsrc[i];
    __syncthreads();

    const int c = tid & 63;   // column 0..63
    const int q = tid >> 6;   // k-quarter 0..3

    float a8[8];
#pragma unroll
    for (int r = 0; r < 8; ++r) a8[r] = 0.0f;

    const float* w;
    int stride;
    if (c < 32)       { w = W_se + c;                  stride = 32; }
    else if (c < 48)  { w = W_span + (c - 32);         stride = 16; }
    else              { w = W_span + Dd * 16 + (c - 48); stride = 16; }

    const int k0 = q * 192;
    for (int k = k0; k < k0 + 192; ++k) {
        const float wv = w[(size_t)k * stride];
#pragma unroll
        for (int r = 0; r < 8; ++r) a8[r] += xs[r * Dd + k] * wv;
    }
#pragma unroll
    for (int r = 0; r < 8; ++r) part[tid * 8 + r] = a8[r];
    __syncthreads();

    if (tid < 64) {
        float z[8];
#pragma unroll
        for (int r = 0; r < 8; ++r)
            z[r] = part[c * 8 + r] + part[(c + 64) * 8 + r] +
                   part[(c + 128) * 8 + r] + part[(c + 192) * 8 + r];

        if (c < 32) {
            // start/end focal loss, masked by n < seqlen[b]
            const int sl = seqlen[b];
            float lsum = 0.0f;
            const float bse = b_se[c];
#pragma unroll
            for (int r = 0; r < 8; ++r) {
                const int n = n0 + r;
                const float zz = z[r] + bse;
                const float p = 1.0f / (1.0f + expf(-zz));
                const float y = (c < 16) ? start[(b * 2 * Ll + c) * Nn + n]
                                         : end[(b * 2 * Ll + (c - 16) - Ll) * Nn + n];
                const float fl = (y == 1.0f)
                    ? (-0.5f * (1.0f - p) * (1.0f - p) * logf(p))
                    : (-0.5f * p * p * logf(1.0f - p));
                if (n < sl) lsum += fl;
            }
            atomicAdd(&s_se, lsum);
        } else if (c < 48) {
            const int l = c - 32;
            const float bsp = b_span[l];
#pragma unroll
            for (int r = 0; r < 8; ++r)
                At[(b * Ll + l) * Nn + n0 + r] = z[r] + bsp;  // bias folded in
        } else {
            const int l = c - 48;
#pragma unroll
            for (int r = 0; r < 8; ++r)
                Bt[(b * Ll + l) * Nn + n0 + r] = z[r];
        }
    }
    __syncthreads();
    if (tid == 0) atomicAdd(&acc[5], s_se);
}

// ---------------------------------------------------------------------------
// Kernel 2: the big [B,L,N,N] pass. Vectorized int4/float4, grid-stride.
// ---------------------------------------------------------------------------
__global__ __launch_bounds__(256) void k_span(
    const float* __restrict__ At, const float* __restrict__ Bt,
    const int* __restrict__ span, const int* __restrict__ val,
    float* __restrict__ out, float* __restrict__ acc)
{
    const long long total4 = (long long)Bsz * Ll * Nn * Nn / 4;  // 8388608
    const int tid = threadIdx.x;
    const long long gstride = (long long)gridDim.x * blockDim.x;

    int tpc = 0, tnc = 0, fpc = 0, vc = 0;
    float ls = 0.0f;

    const int4* s4 = (const int4*)span;
    const int4* v4 = (const int4*)val;
    float4* o4 = (float4*)out;

    for (long long vid = (long long)blockIdx.x * blockDim.x + tid; vid < total4; vid += gstride) {
        const long long ri = vid >> 7;               // (b*L+l)*N + i
        const int j0 = (int)((vid & 127) << 2);
        const float a = At[ri];
        const long long bl = ri >> 9;                // b*L + l
        const float4 bt = *(const float4*)(Bt + (bl << 9) + j0);
        const int4 sp = s4[vid];
        const int4 vv = v4[vid];
        float4 po;

#define DO_ELEM(btj, spv, vvv, pout)                                          \
        {                                                                     \
            const float p = 1.0f / (1.0f + expf(-(a + (btj))));               \
            const int pred = (p > 0.5f) ? 1 : 0;                              \
            (pout) = (float)pred;                                             \
            tpc += ((spv) == 1) & pred;                                       \
            tnc += ((spv) == 1) & (pred ^ 1);                                 \
            fpc += ((spv) == 0) & ((vvv) == 1) & pred;                        \
            vc  += (vvv);                                                     \
            if (vvv) {                                                        \
                const float fl = ((spv) == 1)                                 \
                    ? (-0.5f * (1.0f - p) * (1.0f - p) * logf(p))             \
                    : (-0.5f * p * p * logf(1.0f - p));                       \
                ls += fl;                                                     \
            }                                                                 \
        }

        DO_ELEM(bt.x, sp.x, vv.x, po.x)
        DO_ELEM(bt.y, sp.y, vv.y, po.y)
        DO_ELEM(bt.z, sp.z, vv.z, po.z)
        DO_ELEM(bt.w, sp.w, vv.w, po.w)
#undef DO_ELEM

        o4[vid] = po;
    }

    // wave (64-lane) reduction
    for (int off = 32; off; off >>= 1) {
        tpc += __shfl_down(tpc, off);
        tnc += __shfl_down(tnc, off);
        fpc += __shfl_down(fpc, off);
        vc  += __shfl_down(vc,  off);
        ls  += __shfl_down(ls,  off);
    }

    __shared__ int   si[4][4];
    __shared__ float sf[4];
    const int wave = tid >> 6, lane = tid & 63;
    if (lane == 0) {
        si[wave][0] = tpc; si[wave][1] = tnc; si[wave][2] = fpc; si[wave][3] = vc;
        sf[wave] = ls;
    }
    __syncthreads();
    if (tid == 0) {
        int t0 = 0, t1 = 0, t2 = 0, t3 = 0;
        float f = 0.0f;
        for (int w = 0; w < 4; ++w) {
            t0 += si[w][0]; t1 += si[w][1]; t2 += si[w][2]; t3 += si[w][3];
            f += sf[w];
        }
        unsigned int* accU = (unsigned int*)acc;
        atomicAdd(&accU[0], (unsigned int)t0);
        atomicAdd(&accU[1], (unsigned int)t1);
        atomicAdd(&accU[2], (unsigned int)t2);
        atomicAdd(&accU[3], (unsigned int)t3);
        atomicAdd(&acc[4], f);
    }
}

// ---------------------------------------------------------------------------
// Kernel 3: finalize the 5 scalar outputs
// ---------------------------------------------------------------------------
__global__ void k_fin(const float* __restrict__ acc,
                      const int* __restrict__ seqlen,
                      float* __restrict__ out5)
{
    if (threadIdx.x == 0 && blockIdx.x == 0) {
        const unsigned int* accU = (const unsigned int*)acc;
        int ssum = 0;
        for (int i = 0; i < Bsz; ++i) ssum += seqlen[i];
        out5[0] = (float)accU[0];                                   // tp
        out5[1] = (float)accU[1];                                   // tn
        out5[2] = (float)accU[2];                                   // fp
        out5[3] = acc[5] / (2.0f * Ll * (float)ssum);               // startend_loss
        out5[4] = acc[4] / ((float)accU[3] + 1e-6f);                // span_loss
    }
}

extern "C" void kernel_launch(void* const* d_in, const int* in_sizes, int n_in,
                              void* d_out, int out_size, void* d_ws, size_t ws_size,
                              hipStream_t stream) {
    const float* x      = (const float*)d_in[0];
    const float* start  = (const float*)d_in[1];
    const float* end    = (const float*)d_in[2];
    const int*   span   = (const int*)d_in[3];
    const int*   val    = (const int*)d_in[4];
    const int*   seqlen = (const int*)d_in[5];
    const float* W_se   = (const float*)d_in[6];
    const float* b_se   = (const float*)d_in[7];
    const float* W_span = (const float*)d_in[8];
    const float* b_span = (const float*)d_in[9];

    float* out = (float*)d_out;

    const size_t n_at = (size_t)Bsz * Ll * Nn;    // 65536
    float* At  = (float*)d_ws;
    float* Bt  = At + n_at;
    float* acc = Bt + n_at;

    hipMemsetAsync(acc, 0, 8 * sizeof(float), stream);

    k_prep<<<Bsz * (Nn / 8), 256, 0, stream>>>(x, start, end, seqlen,
                                               W_se, b_se, W_span, b_span,
                                               At, Bt, acc);

    const long long total_elems = (long long)Bsz * Ll * Nn * Nn;   // 33554432
    k_span<<<4096, 256, 0, stream>>>(At, Bt, span, val, out, acc);

    k_fin<<<1, 64, 0, stream>>>(acc, seqlen, out + total_elems);
}